// Round 1
// baseline (117.025 us; speedup 1.0000x reference)
//
#include <hip/hip_runtime.h>

#define TPB 256
#define RPB 16          // rows per block -> grid = 8 * 128 = 1024 blocks
#define SEQ_L 2048
#define NBATCH 8

static constexpr float kBondTol  = 0.4f;
static constexpr float kClashTol = 1.5f;
static constexpr float kIdeal    = 3.8f;
static constexpr float kEps      = 1e-8f;

__device__ __forceinline__ float wred(float v) {
#pragma unroll
  for (int o = 32; o > 0; o >>= 1) v += __shfl_down(v, o, 64);
  return v;
}

__global__ __launch_bounds__(TPB) void viol_main(
    const float* __restrict__ pos,    // [B, L, 3]
    const float* __restrict__ mask,   // [B, L]
    float* __restrict__ acc) {        // [4]: bv, bm, cv, pm
  __shared__ float4 s[SEQ_L];         // x, y, z, mask  (32 KB)
  __shared__ float  redm[TPB / 64];
  __shared__ float  red4[TPB / 64][4];

  const int blocks_per_b = SEQ_L / RPB;
  const int b  = blockIdx.x / blocks_per_b;
  const int i0 = (blockIdx.x % blocks_per_b) * RPB;
  const float* pb = pos  + (size_t)b * SEQ_L * 3;
  const float* mb = mask + (size_t)b * SEQ_L;

  // ---- stage batch into LDS, accumulate mask-sum on the side ----
  float mpart = 0.f;
  for (int idx = threadIdx.x; idx < SEQ_L; idx += TPB) {
    float x = pb[3 * idx + 0];
    float y = pb[3 * idx + 1];
    float z = pb[3 * idx + 2];
    float m = mb[idx];
    s[idx] = make_float4(x, y, z, m);
    mpart += m;
  }
  mpart = wred(mpart);
  const int wid  = threadIdx.x >> 6;
  const int lane = threadIdx.x & 63;
  if (lane == 0) redm[wid] = mpart;
  __syncthreads();
  const float msum = redm[0] + redm[1] + redm[2] + redm[3];

  float cv = 0.f, pm = 0.f, bv = 0.f, bm = 0.f;

  // ---- main all-pairs loop: full row sums (no seq-sep predicate) ----
  for (int r = 0; r < RPB; ++r) {
    const int i = i0 + r;
    const float4 pi = s[i];
    float rowsum = 0.f;
#pragma unroll
    for (int j = threadIdx.x; j < SEQ_L; j += TPB) {   // 8 iterations
      float4 pj = s[j];
      float dx = pj.x - pi.x;
      float dy = pj.y - pi.y;
      float dz = pj.z - pi.z;
      float d2 = dx * dx + dy * dy + dz * dz;
      float dist = __builtin_amdgcn_sqrtf(d2 + kEps);
      rowsum += fmaxf(kClashTol - dist, 0.f) * pj.w;
    }
    cv += pi.w * rowsum;
  }

  // ---- near-diagonal correction (|i-j| <= 2) + bond term + analytic pm ----
  if (threadIdx.x < RPB) {
    const int i = i0 + threadIdx.x;
    const float4 pi = s[i];
    float nv = 0.f, nm = 0.f;
    const int jlo = (i - 2 < 0) ? 0 : i - 2;
    const int jhi = (i + 2 > SEQ_L - 1) ? SEQ_L - 1 : i + 2;
    for (int j = jlo; j <= jhi; ++j) {
      float4 pj = s[j];
      float dx = pj.x - pi.x;
      float dy = pj.y - pi.y;
      float dz = pj.z - pi.z;
      float dist = __builtin_amdgcn_sqrtf(dx * dx + dy * dy + dz * dz + kEps);
      nv += fmaxf(kClashTol - dist, 0.f) * pj.w;
      nm += pj.w;
    }
    cv -= pi.w * nv;                 // remove |i-j|<=2 from the full sum
    pm += pi.w * (msum - nm);        // analytic pair-mask row sum

    if (i < SEQ_L - 1) {
      const float4 pj = s[i + 1];
      float dx = pj.x - pi.x;
      float dy = pj.y - pi.y;
      float dz = pj.z - pi.z;
      float dist = __builtin_amdgcn_sqrtf(dx * dx + dy * dy + dz * dz + kEps);
      float viol = fmaxf(fabsf(dist - kIdeal) - kBondTol, 0.f);
      bv += viol * pi.w * pj.w;
      bm += pi.w * pj.w;
    }
  }

  // ---- block reduction -> one atomic per accumulator per block ----
  bv = wred(bv); bm = wred(bm); cv = wred(cv); pm = wred(pm);
  if (lane == 0) {
    red4[wid][0] = bv; red4[wid][1] = bm;
    red4[wid][2] = cv; red4[wid][3] = pm;
  }
  __syncthreads();
  if (threadIdx.x == 0) {
    float tbv = 0.f, tbm = 0.f, tcv = 0.f, tpm = 0.f;
#pragma unroll
    for (int w = 0; w < TPB / 64; ++w) {
      tbv += red4[w][0]; tbm += red4[w][1];
      tcv += red4[w][2]; tpm += red4[w][3];
    }
    atomicAdd(&acc[0], tbv);
    atomicAdd(&acc[1], tbm);
    atomicAdd(&acc[2], tcv);
    atomicAdd(&acc[3], tpm);
  }
}

__global__ void viol_final(const float* __restrict__ acc, float* __restrict__ out) {
  float bond  = acc[0] / (acc[1] + kEps);
  float clash = acc[2] / (acc[3] + kEps);
  out[0] = bond;
  out[1] = clash;
  out[2] = bond + clash;
}

extern "C" void kernel_launch(void* const* d_in, const int* in_sizes, int n_in,
                              void* d_out, int out_size, void* d_ws, size_t ws_size,
                              hipStream_t stream) {
  const float* pos  = (const float*)d_in[0];
  const float* mask = (const float*)d_in[1];
  float* out = (float*)d_out;
  float* acc = (float*)d_ws;

  hipMemsetAsync(acc, 0, 4 * sizeof(float), stream);
  viol_main<<<dim3(NBATCH * (SEQ_L / RPB)), dim3(TPB), 0, stream>>>(pos, mask, acc);
  viol_final<<<1, 1, 0, stream>>>(acc, out);
}

// Round 2
// 71.369 us; speedup vs baseline: 1.6397x; 1.6397x over previous
//
#include <hip/hip_runtime.h>

#define TPB 256
#define RPB 16                         // rows per block
#define JPT (SEQ_L / TPB)              // j-iterations per thread = 8
#define SEQ_L 2048
#define NBATCH 8
#define NBLOCKS (NBATCH * (SEQ_L / RPB))   // 1024

static constexpr float kBondTol  = 0.4f;
static constexpr float kClashTol = 1.5f;
static constexpr float kIdeal    = 3.8f;
static constexpr float kEps      = 1e-8f;

__device__ __forceinline__ float wred(float v) {
#pragma unroll
  for (int o = 32; o > 0; o >>= 1) v += __shfl_down(v, o, 64);
  return v;
}

__global__ __launch_bounds__(TPB, 4) void viol_main(
    const float* __restrict__ pos,    // [B, L, 3]
    const float* __restrict__ mask,   // [B, L]
    float4* __restrict__ partial) {   // [NBLOCKS]: (bv, bm, cv, pm)
  __shared__ float4 s[SEQ_L];         // x, y, z, mask  (32 KB)
  __shared__ float  redm[TPB / 64];
  __shared__ float  red4[TPB / 64][4];

  const int blocks_per_b = SEQ_L / RPB;
  const int b  = blockIdx.x / blocks_per_b;
  const int i0 = (blockIdx.x % blocks_per_b) * RPB;
  const float* pb = pos  + (size_t)b * SEQ_L * 3;
  const float* mb = mask + (size_t)b * SEQ_L;

  // ---- stage batch into LDS, accumulate mask-sum on the side ----
  float mpart = 0.f;
  for (int idx = threadIdx.x; idx < SEQ_L; idx += TPB) {
    float x = pb[3 * idx + 0];
    float y = pb[3 * idx + 1];
    float z = pb[3 * idx + 2];
    float m = mb[idx];
    s[idx] = make_float4(x, y, z, m);
    mpart += m;
  }
  mpart = wred(mpart);
  const int wid  = threadIdx.x >> 6;
  const int lane = threadIdx.x & 63;
  if (lane == 0) redm[wid] = mpart;
  __syncthreads();
  const float msum = redm[0] + redm[1] + redm[2] + redm[3];

  // ---- register tile: 16 rows in registers, stream pj once for all rows ----
  float px[RPB], py[RPB], pz[RPB], pw[RPB], accr[RPB];
#pragma unroll
  for (int r = 0; r < RPB; ++r) {
    float4 p = s[i0 + r];             // broadcast read (conflict-free)
    px[r] = p.x; py[r] = p.y; pz[r] = p.z; pw[r] = p.w;
    accr[r] = 0.f;
  }

#pragma unroll
  for (int k = 0; k < JPT; ++k) {
    float4 pj = s[threadIdx.x + k * TPB];
#pragma unroll
    for (int r = 0; r < RPB; ++r) {
      float dx = pj.x - px[r];
      float dy = pj.y - py[r];
      float dz = pj.z - pz[r];
      float d2 = fmaf(dx, dx, fmaf(dy, dy, dz * dz)) + kEps;
      float dist = __builtin_amdgcn_sqrtf(d2);
      accr[r] = fmaf(fmaxf(kClashTol - dist, 0.f), pj.w, accr[r]);
    }
  }

  float cv = 0.f, pm = 0.f, bv = 0.f, bm = 0.f;
#pragma unroll
  for (int r = 0; r < RPB; ++r) cv = fmaf(pw[r], accr[r], cv);

  // ---- near-diagonal correction (|i-j| <= 2) + bond term + analytic pm ----
  if (threadIdx.x < RPB) {
    const int i = i0 + threadIdx.x;
    const float4 pi = s[i];
    float nv = 0.f, nm = 0.f;
    const int jlo = (i - 2 < 0) ? 0 : i - 2;
    const int jhi = (i + 2 > SEQ_L - 1) ? SEQ_L - 1 : i + 2;
    for (int j = jlo; j <= jhi; ++j) {
      float4 pj = s[j];
      float dx = pj.x - pi.x;
      float dy = pj.y - pi.y;
      float dz = pj.z - pi.z;
      float dist = __builtin_amdgcn_sqrtf(dx * dx + dy * dy + dz * dz + kEps);
      nv += fmaxf(kClashTol - dist, 0.f) * pj.w;
      nm += pj.w;
    }
    cv -= pi.w * nv;                 // remove |i-j|<=2 from the full sum
    pm += pi.w * (msum - nm);        // analytic pair-mask row sum

    if (i < SEQ_L - 1) {
      const float4 pj = s[i + 1];
      float dx = pj.x - pi.x;
      float dy = pj.y - pi.y;
      float dz = pj.z - pi.z;
      float dist = __builtin_amdgcn_sqrtf(dx * dx + dy * dy + dz * dz + kEps);
      float viol = fmaxf(fabsf(dist - kIdeal) - kBondTol, 0.f);
      bv += viol * pi.w * pj.w;
      bm += pi.w * pj.w;
    }
  }

  // ---- block reduction -> ONE plain float4 store per block (no atomics) ----
  bv = wred(bv); bm = wred(bm); cv = wred(cv); pm = wred(pm);
  if (lane == 0) {
    red4[wid][0] = bv; red4[wid][1] = bm;
    red4[wid][2] = cv; red4[wid][3] = pm;
  }
  __syncthreads();
  if (threadIdx.x == 0) {
    float tbv = 0.f, tbm = 0.f, tcv = 0.f, tpm = 0.f;
#pragma unroll
    for (int w = 0; w < TPB / 64; ++w) {
      tbv += red4[w][0]; tbm += red4[w][1];
      tcv += red4[w][2]; tpm += red4[w][3];
    }
    partial[blockIdx.x] = make_float4(tbv, tbm, tcv, tpm);
  }
}

__global__ __launch_bounds__(TPB) void viol_reduce(
    const float4* __restrict__ partial, float* __restrict__ out) {
  __shared__ float red4[TPB / 64][4];
  float bv = 0.f, bm = 0.f, cv = 0.f, pm = 0.f;
#pragma unroll
  for (int i = threadIdx.x; i < NBLOCKS; i += TPB) {
    float4 p = partial[i];
    bv += p.x; bm += p.y; cv += p.z; pm += p.w;
  }
  bv = wred(bv); bm = wred(bm); cv = wred(cv); pm = wred(pm);
  const int wid  = threadIdx.x >> 6;
  const int lane = threadIdx.x & 63;
  if (lane == 0) {
    red4[wid][0] = bv; red4[wid][1] = bm;
    red4[wid][2] = cv; red4[wid][3] = pm;
  }
  __syncthreads();
  if (threadIdx.x == 0) {
    float tbv = 0.f, tbm = 0.f, tcv = 0.f, tpm = 0.f;
#pragma unroll
    for (int w = 0; w < TPB / 64; ++w) {
      tbv += red4[w][0]; tbm += red4[w][1];
      tcv += red4[w][2]; tpm += red4[w][3];
    }
    float bond  = tbv / (tbm + kEps);
    float clash = tcv / (tpm + kEps);
    out[0] = bond;
    out[1] = clash;
    out[2] = bond + clash;
  }
}

extern "C" void kernel_launch(void* const* d_in, const int* in_sizes, int n_in,
                              void* d_out, int out_size, void* d_ws, size_t ws_size,
                              hipStream_t stream) {
  const float* pos  = (const float*)d_in[0];
  const float* mask = (const float*)d_in[1];
  float* out = (float*)d_out;
  float4* partial = (float4*)d_ws;   // 1024 * 16 B = 16 KB scratch

  viol_main<<<dim3(NBLOCKS), dim3(TPB), 0, stream>>>(pos, mask, partial);
  viol_reduce<<<dim3(1), dim3(TPB), 0, stream>>>(partial, out);
}

// Round 3
// 67.164 us; speedup vs baseline: 1.7424x; 1.0626x over previous
//
#include <hip/hip_runtime.h>

#define TPB 256
#define RPB 16                         // rows per block (register tile)
#define SEQ_L 2048
#define JPT (SEQ_L / TPB)              // j-iterations per thread = 8
#define NBATCH 8
#define NBLOCKS (NBATCH * (SEQ_L / RPB))   // 1024

static constexpr float kBondTol  = 0.4f;
static constexpr float kClashTol = 1.5f;
static constexpr float kIdeal    = 3.8f;
static constexpr float kEps      = 1e-8f;
static constexpr float kThresh2  = 2.25f;   // 1.5^2: d2 >= this -> relu == 0

__device__ __forceinline__ float wred(float v) {
#pragma unroll
  for (int o = 32; o > 0; o >>= 1) v += __shfl_down(v, o, 64);
  return v;
}

__global__ __launch_bounds__(TPB, 4) void viol_main(
    const float* __restrict__ pos,    // [B, L, 3]
    const float* __restrict__ mask,   // [B, L]
    float4* __restrict__ partial) {   // [NBLOCKS]: (bv, bm, cv, pm)
  __shared__ float4 s[SEQ_L];         // x, y, z, mask  (32 KB)
  __shared__ float  redm[TPB / 64];
  __shared__ float  red4[TPB / 64][4];

  const int blocks_per_b = SEQ_L / RPB;
  const int b  = blockIdx.x / blocks_per_b;
  const int i0 = (blockIdx.x % blocks_per_b) * RPB;
  const float* pb = pos  + (size_t)b * SEQ_L * 3;
  const float* mb = mask + (size_t)b * SEQ_L;

  // ---- stage batch into LDS, accumulate mask-sum on the side ----
  float mpart = 0.f;
  for (int idx = threadIdx.x; idx < SEQ_L; idx += TPB) {
    float x = pb[3 * idx + 0];
    float y = pb[3 * idx + 1];
    float z = pb[3 * idx + 2];
    float m = mb[idx];
    s[idx] = make_float4(x, y, z, m);
    mpart += m;
  }
  mpart = wred(mpart);
  const int wid  = threadIdx.x >> 6;
  const int lane = threadIdx.x & 63;
  if (lane == 0) redm[wid] = mpart;
  __syncthreads();
  const float msum = redm[0] + redm[1] + redm[2] + redm[3];

  // ---- register tile: 16 rows in registers ----
  float px[RPB], py[RPB], pz[RPB], pw[RPB], accr[RPB];
#pragma unroll
  for (int r = 0; r < RPB; ++r) {
    float4 p = s[i0 + r];             // broadcast read (conflict-free)
    px[r] = p.x; py[r] = p.y; pz[r] = p.z; pw[r] = p.w;
    accr[r] = 0.f;
  }

  // ---- all-pairs loop: d2-only common path, wave-uniform sqrt skip ----
  // Data is N(0,10): P(d2 < 2.25) ~ 3e-4, so the sqrt block runs for only
  // ~28% of (wave, k) groups. Skip is exact: d2 >= 2.25 -> relu == 0.
#pragma unroll 2
  for (int k = 0; k < JPT; ++k) {
    float4 pj = s[threadIdx.x + k * TPB];
    float d2r[RPB];
    float minv;
#pragma unroll
    for (int r = 0; r < RPB; ++r) {
      float dx = pj.x - px[r];
      float dy = pj.y - py[r];
      float dz = pj.z - pz[r];
      float d2 = fmaf(dx, dx, fmaf(dy, dy, dz * dz));
      d2r[r] = d2;
      minv = (r == 0) ? d2 : fminf(minv, d2);
    }
    if (__ballot(minv < kThresh2) != 0ull) {   // any lane in any row clashes
#pragma unroll
      for (int r = 0; r < RPB; ++r) {
        float dist = __builtin_amdgcn_sqrtf(d2r[r] + kEps);
        accr[r] = fmaf(fmaxf(kClashTol - dist, 0.f), pj.w, accr[r]);
      }
    }
  }

  float cv = 0.f, pm = 0.f, bv = 0.f, bm = 0.f;
#pragma unroll
  for (int r = 0; r < RPB; ++r) cv = fmaf(pw[r], accr[r], cv);

  // ---- near-diagonal correction (|i-j| <= 2) + bond term + analytic pm ----
  if (threadIdx.x < RPB) {
    const int i = i0 + threadIdx.x;
    const float4 pi = s[i];
    float nv = 0.f, nm = 0.f;
    const int jlo = (i - 2 < 0) ? 0 : i - 2;
    const int jhi = (i + 2 > SEQ_L - 1) ? SEQ_L - 1 : i + 2;
    for (int j = jlo; j <= jhi; ++j) {
      float4 pj = s[j];
      float dx = pj.x - pi.x;
      float dy = pj.y - pi.y;
      float dz = pj.z - pi.z;
      float dist = __builtin_amdgcn_sqrtf(dx * dx + dy * dy + dz * dz + kEps);
      nv += fmaxf(kClashTol - dist, 0.f) * pj.w;
      nm += pj.w;
    }
    cv -= pi.w * nv;                 // remove |i-j|<=2 from the full sum
    pm += pi.w * (msum - nm);        // analytic pair-mask row sum

    if (i < SEQ_L - 1) {
      const float4 pj = s[i + 1];
      float dx = pj.x - pi.x;
      float dy = pj.y - pi.y;
      float dz = pj.z - pi.z;
      float dist = __builtin_amdgcn_sqrtf(dx * dx + dy * dy + dz * dz + kEps);
      float viol = fmaxf(fabsf(dist - kIdeal) - kBondTol, 0.f);
      bv += viol * pi.w * pj.w;
      bm += pi.w * pj.w;
    }
  }

  // ---- block reduction -> ONE plain float4 store per block (no atomics) ----
  bv = wred(bv); bm = wred(bm); cv = wred(cv); pm = wred(pm);
  if (lane == 0) {
    red4[wid][0] = bv; red4[wid][1] = bm;
    red4[wid][2] = cv; red4[wid][3] = pm;
  }
  __syncthreads();
  if (threadIdx.x == 0) {
    float tbv = 0.f, tbm = 0.f, tcv = 0.f, tpm = 0.f;
#pragma unroll
    for (int w = 0; w < TPB / 64; ++w) {
      tbv += red4[w][0]; tbm += red4[w][1];
      tcv += red4[w][2]; tpm += red4[w][3];
    }
    partial[blockIdx.x] = make_float4(tbv, tbm, tcv, tpm);
  }
}

__global__ __launch_bounds__(TPB) void viol_reduce(
    const float4* __restrict__ partial, float* __restrict__ out) {
  __shared__ float red4[TPB / 64][4];
  float bv = 0.f, bm = 0.f, cv = 0.f, pm = 0.f;
#pragma unroll
  for (int i = threadIdx.x; i < NBLOCKS; i += TPB) {
    float4 p = partial[i];
    bv += p.x; bm += p.y; cv += p.z; pm += p.w;
  }
  bv = wred(bv); bm = wred(bm); cv = wred(cv); pm = wred(pm);
  const int wid  = threadIdx.x >> 6;
  const int lane = threadIdx.x & 63;
  if (lane == 0) {
    red4[wid][0] = bv; red4[wid][1] = bm;
    red4[wid][2] = cv; red4[wid][3] = pm;
  }
  __syncthreads();
  if (threadIdx.x == 0) {
    float tbv = 0.f, tbm = 0.f, tcv = 0.f, tpm = 0.f;
#pragma unroll
    for (int w = 0; w < TPB / 64; ++w) {
      tbv += red4[w][0]; tbm += red4[w][1];
      tcv += red4[w][2]; tpm += red4[w][3];
    }
    float bond  = tbv / (tbm + kEps);
    float clash = tcv / (tpm + kEps);
    out[0] = bond;
    out[1] = clash;
    out[2] = bond + clash;
  }
}

extern "C" void kernel_launch(void* const* d_in, const int* in_sizes, int n_in,
                              void* d_out, int out_size, void* d_ws, size_t ws_size,
                              hipStream_t stream) {
  const float* pos  = (const float*)d_in[0];
  const float* mask = (const float*)d_in[1];
  float* out = (float*)d_out;
  float4* partial = (float4*)d_ws;   // 1024 * 16 B = 16 KB scratch

  viol_main<<<dim3(NBLOCKS), dim3(TPB), 0, stream>>>(pos, mask, partial);
  viol_reduce<<<dim3(1), dim3(TPB), 0, stream>>>(partial, out);
}

// Round 4
// 63.965 us; speedup vs baseline: 1.8295x; 1.0500x over previous
//
#include <hip/hip_runtime.h>

#define TPB 256
#define RPB 16                         // rows per block (register tile)
#define SEQ_L 2048
#define JPT (SEQ_L / TPB)              // 256-wide j-chunks = 8
#define NBATCH 8
#define NBLOCKS (NBATCH * (SEQ_L / RPB))   // 1024

static constexpr float kBondTol  = 0.4f;
static constexpr float kClashTol = 1.5f;
static constexpr float kIdeal    = 3.8f;
static constexpr float kEps      = 1e-8f;
static constexpr float kThresh2  = 2.25f;   // 1.5^2: d2 >= this -> relu == 0

__device__ __forceinline__ float wred(float v) {
#pragma unroll
  for (int o = 32; o > 0; o >>= 1) v += __shfl_down(v, o, 64);
  return v;
}

__global__ __launch_bounds__(TPB, 4) void viol_main(
    const float* __restrict__ pos,    // [B, L, 3]
    const float* __restrict__ mask,   // [B, L]
    float4* __restrict__ partial) {   // [NBLOCKS]: (bv, bm, 2*cv_half, pm)
  __shared__ float4 s[SEQ_L];         // x, y, z, mask  (32 KB)
  __shared__ float  redm[TPB / 64];
  __shared__ float  red4[TPB / 64][4];

  // ---- balanced tile permutation for the triangular workload ----
  // b = blockIdx & 7, u = blockIdx >> 3.  Blocks land on a CU at stride 256
  // (u-stride 32); tiles {2r, 127-2r, 2r+1, 126-2r} make any such group's
  // total k-iters constant (sum of tile indices = 254 for every r).
  const int u = blockIdx.x >> 3;
  const int b = blockIdx.x & 7;
  const int v = u >> 5, rr = u & 31;
  int tile;
  if      (v == 0) tile = 2 * rr;
  else if (v == 1) tile = 127 - 2 * rr;
  else if (v == 2) tile = 2 * rr + 1;
  else             tile = 126 - 2 * rr;
  const int i0 = tile << 4;

  const float* pb = pos  + (size_t)b * SEQ_L * 3;
  const float* mb = mask + (size_t)b * SEQ_L;

  // ---- stage batch into LDS, accumulate mask-sum on the side ----
  float mpart = 0.f;
  for (int idx = threadIdx.x; idx < SEQ_L; idx += TPB) {
    float x = pb[3 * idx + 0];
    float y = pb[3 * idx + 1];
    float z = pb[3 * idx + 2];
    float m = mb[idx];
    s[idx] = make_float4(x, y, z, m);
    mpart += m;
  }
  mpart = wred(mpart);
  const int wid  = threadIdx.x >> 6;
  const int lane = threadIdx.x & 63;
  if (lane == 0) redm[wid] = mpart;
  __syncthreads();
  const float msum = redm[0] + redm[1] + redm[2] + redm[3];

  // ---- register tile: 16 rows in registers ----
  float px[RPB], py[RPB], pz[RPB], pw[RPB], accr[RPB];
#pragma unroll
  for (int r = 0; r < RPB; ++r) {
    float4 p = s[i0 + r];             // broadcast read (conflict-free)
    px[r] = p.x; py[r] = p.y; pz[r] = p.z; pw[r] = p.w;
    accr[r] = 0.f;
  }

  // ---- boundary j-chunk (contains the diagonal): masked, always-sqrt ----
  const int k0 = i0 >> 8;             // 256-chunk containing this tile
  {
    const int j = threadIdx.x + (k0 << 8);
    const float4 pj = s[j];
#pragma unroll
    for (int r = 0; r < RPB; ++r) {
      const int i = i0 + r;
      float dx = pj.x - px[r];
      float dy = pj.y - py[r];
      float dz = pj.z - pz[r];
      float d2 = fmaf(dx, dx, fmaf(dy, dy, dz * dz));
      float dist = __builtin_amdgcn_sqrtf(d2 + kEps);
      float mw = (j > i) ? pj.w : 0.f;          // strict upper triangle
      accr[r] = fmaf(fmaxf(kClashTol - dist, 0.f), mw, accr[r]);
    }
  }

  // ---- full j-chunks above the tile: d2-only + wave-uniform sqrt skip ----
#pragma unroll 2
  for (int k = k0 + 1; k < JPT; ++k) {
    float4 pj = s[threadIdx.x + (k << 8)];
    float d2r[RPB];
#pragma unroll
    for (int r = 0; r < RPB; ++r) {
      float dx = pj.x - px[r];
      float dy = pj.y - py[r];
      float dz = pj.z - pz[r];
      d2r[r] = fmaf(dx, dx, fmaf(dy, dy, dz * dz));
    }
    float mv = d2r[0];
#pragma unroll
    for (int r = 1; r < RPB; ++r) mv = fminf(mv, d2r[r]);   // fuses to min3
    if (__ballot(mv < kThresh2) != 0ull) {
#pragma unroll
      for (int r = 0; r < RPB; ++r) {
        float dist = __builtin_amdgcn_sqrtf(d2r[r] + kEps);
        accr[r] = fmaf(fmaxf(kClashTol - dist, 0.f), pj.w, accr[r]);
      }
    }
  }

  float cv = 0.f, pm = 0.f, bv = 0.f, bm = 0.f;
#pragma unroll
  for (int r = 0; r < RPB; ++r) cv = fmaf(pw[r], accr[r], cv);

  // ---- near-diagonal correction (i < j <= i+2) + bond + analytic pm ----
  if (threadIdx.x < RPB) {
    const int i = i0 + threadIdx.x;
    const float4 pi = s[i];
    // subtract j = i+1, i+2 (strict upper near-diagonal) from the clash sum
    float nv = 0.f;
    const int jhi = (i + 2 > SEQ_L - 1) ? SEQ_L - 1 : i + 2;
    for (int j = i + 1; j <= jhi; ++j) {
      float4 pj = s[j];
      float dx = pj.x - pi.x;
      float dy = pj.y - pi.y;
      float dz = pj.z - pi.z;
      float dist = __builtin_amdgcn_sqrtf(dx * dx + dy * dy + dz * dz + kEps);
      nv += fmaxf(kClashTol - dist, 0.f) * pj.w;
    }
    cv -= pi.w * nv;

    // analytic pair-mask row sum (ordered, full |i-j|<=2 window incl. j==i)
    float nm = 0.f;
    const int jlo = (i - 2 < 0) ? 0 : i - 2;
    for (int j = jlo; j <= jhi; ++j) nm += s[j].w;
    pm += pi.w * (msum - nm);

    // bond term
    if (i < SEQ_L - 1) {
      const float4 pj = s[i + 1];
      float dx = pj.x - pi.x;
      float dy = pj.y - pi.y;
      float dz = pj.z - pi.z;
      float dist = __builtin_amdgcn_sqrtf(dx * dx + dy * dy + dz * dz + kEps);
      float viol = fmaxf(fabsf(dist - kIdeal) - kBondTol, 0.f);
      bv += viol * pi.w * pj.w;
      bm += pi.w * pj.w;
    }
  }

  // ---- block reduction -> ONE plain float4 store per block (no atomics) ----
  bv = wred(bv); bm = wred(bm); cv = wred(cv); pm = wred(pm);
  if (lane == 0) {
    red4[wid][0] = bv; red4[wid][1] = bm;
    red4[wid][2] = cv; red4[wid][3] = pm;
  }
  __syncthreads();
  if (threadIdx.x == 0) {
    float tbv = 0.f, tbm = 0.f, tcv = 0.f, tpm = 0.f;
#pragma unroll
    for (int w = 0; w < TPB / 64; ++w) {
      tbv += red4[w][0]; tbm += red4[w][1];
      tcv += red4[w][2]; tpm += red4[w][3];
    }
    // x2: upper triangle -> full ordered sum
    partial[blockIdx.x] = make_float4(tbv, tbm, 2.f * tcv, tpm);
  }
}

__global__ __launch_bounds__(TPB) void viol_reduce(
    const float4* __restrict__ partial, float* __restrict__ out) {
  __shared__ float red4[TPB / 64][4];
  float bv = 0.f, bm = 0.f, cv = 0.f, pm = 0.f;
#pragma unroll
  for (int i = threadIdx.x; i < NBLOCKS; i += TPB) {
    float4 p = partial[i];
    bv += p.x; bm += p.y; cv += p.z; pm += p.w;
  }
  bv = wred(bv); bm = wred(bm); cv = wred(cv); pm = wred(pm);
  const int wid  = threadIdx.x >> 6;
  const int lane = threadIdx.x & 63;
  if (lane == 0) {
    red4[wid][0] = bv; red4[wid][1] = bm;
    red4[wid][2] = cv; red4[wid][3] = pm;
  }
  __syncthreads();
  if (threadIdx.x == 0) {
    float tbv = 0.f, tbm = 0.f, tcv = 0.f, tpm = 0.f;
#pragma unroll
    for (int w = 0; w < TPB / 64; ++w) {
      tbv += red4[w][0]; tbm += red4[w][1];
      tcv += red4[w][2]; tpm += red4[w][3];
    }
    float bond  = tbv / (tbm + kEps);
    float clash = tcv / (tpm + kEps);
    out[0] = bond;
    out[1] = clash;
    out[2] = bond + clash;
  }
}

extern "C" void kernel_launch(void* const* d_in, const int* in_sizes, int n_in,
                              void* d_out, int out_size, void* d_ws, size_t ws_size,
                              hipStream_t stream) {
  const float* pos  = (const float*)d_in[0];
  const float* mask = (const float*)d_in[1];
  float* out = (float*)d_out;
  float4* partial = (float4*)d_ws;   // 1024 * 16 B = 16 KB scratch

  viol_main<<<dim3(NBLOCKS), dim3(TPB), 0, stream>>>(pos, mask, partial);
  viol_reduce<<<dim3(1), dim3(TPB), 0, stream>>>(partial, out);
}